// Round 12
// baseline (109.184 us; speedup 1.0000x reference)
//
#include <hip/hip_runtime.h>
#include <hip/hip_bf16.h>

#define B_ 64
#define L_ 512
#define H_ 1024
#define EPS_ 1e-13f

typedef unsigned short u16;
typedef __attribute__((ext_vector_type(8))) short s16x8;
typedef __attribute__((ext_vector_type(4))) float f32x4;

__device__ __forceinline__ u16 f2bf(float f) {
  __hip_bfloat16 h = __float2bfloat16(f);
  union { __hip_bfloat16 h; u16 u; } c; c.h = h; return c.u;
}

// ---- Kernel 1: row softmax + mask renorm -> W bf16 (unchanged). ----
__global__ __launch_bounds__(256) void softmax_rows(const float* __restrict__ att,
                                                    const float* __restrict__ mask,
                                                    u16* __restrict__ Wout) {
  const int w = threadIdx.x >> 6, lane = threadIdx.x & 63;
  const int row0 = blockIdx.x * 16 + w * 4;

  float a[4][8];
#pragma unroll
  for (int r = 0; r < 4; ++r) {
    const float* p = att + (size_t)(row0 + r) * L_ + lane * 8;
    float4 v0 = *(const float4*)p;
    float4 v1 = *(const float4*)(p + 4);
    a[r][0] = v0.x; a[r][1] = v0.y; a[r][2] = v0.z; a[r][3] = v0.w;
    a[r][4] = v1.x; a[r][5] = v1.y; a[r][6] = v1.z; a[r][7] = v1.w;
  }

  float m[4];
#pragma unroll
  for (int r = 0; r < 4; ++r) {
    m[r] = a[r][0];
#pragma unroll
    for (int j = 1; j < 8; ++j) m[r] = fmaxf(m[r], a[r][j]);
  }
#pragma unroll
  for (int off = 32; off > 0; off >>= 1)
#pragma unroll
    for (int r = 0; r < 4; ++r) m[r] = fmaxf(m[r], __shfl_xor(m[r], off));

  float z[4] = {0.f, 0.f, 0.f, 0.f};
#pragma unroll
  for (int r = 0; r < 4; ++r)
#pragma unroll
    for (int j = 0; j < 8; ++j) { a[r][j] = __expf(a[r][j] - m[r]); z[r] += a[r][j]; }
#pragma unroll
  for (int off = 32; off > 0; off >>= 1)
#pragma unroll
    for (int r = 0; r < 4; ++r) z[r] += __shfl_xor(z[r], off);

#pragma unroll
  for (int r = 0; r < 4; ++r) {
    const float mk = mask[row0 + r];
    const float c = (1.0f / z[r]) * (mk / (mk + EPS_));  // softmax row-sum == 1
    union { u16 u[8]; uint4 v; } wv;
#pragma unroll
    for (int j = 0; j < 8; ++j) wv.u[j] = f2bf(a[r][j] * c);
    *(uint4*)(Wout + (size_t)(row0 + r) * L_ + lane * 8) = wv.v;
  }
}

#define GLOAD(gp, lp)                                                              \
  __builtin_amdgcn_global_load_lds((const __attribute__((address_space(1))) unsigned*)(gp), \
                                   (__attribute__((address_space(3))) unsigned*)(void*)(lp), 16, 0, 0)

// ---- Kernel 2: GEMM out = W @ X, M=256 x N=128 tile, 8 waves (4x2 of 64x64).
// acc = 64 VGPR/thread -> __launch_bounds__(512,4) caps regs at 128 -> 16
// waves/CU = TWO independent blocks per CU (TLP hides DRAM stalls; the
// lockstep-barrier single-block structure was pinned at ~3 TB/s).
// LDS 64KB: A bf16 ring-2 x16KB @0; B f32 ring-2 x16KB @32768.
// B read column-wise at LDS-read time (b32 gather, <=2-way banks via
// odd-octet source granule^4 pre-swizzle). X slab shared by mt-pair (L2).
__global__ __launch_bounds__(512, 4) void gemm_xd(const u16* __restrict__ Wm,
                                                  const float* __restrict__ X,
                                                  float* __restrict__ out) {
  const int NT = 16;  // K=512 / 32
  // XCD swizzle; logical order: mt fastest (mt-pair shares X slab), then nt, b.
  const int lg = (blockIdx.x & 7) * 128 + (blockIdx.x >> 3);
  const int mt = lg & 1;          // M=512 -> 2 tiles of 256
  const int nt = (lg >> 1) & 7;   // H=1024 -> 8 tiles of 128
  const int b  = lg >> 4;

  __shared__ __align__(16) char lds[65536];

  const int t = threadIdx.x;
  const int lane = t & 63;
  const int w = t >> 6;               // 8 waves
  const int wm = w >> 1, wn = w & 1;  // 4x2 wave grid, 64x64 out each

  const u16* gW = Wm + ((size_t)b * L_ + mt * 256) * L_;
  const float* gX = X + (size_t)b * L_ * H_ + nt * 128;

  // A staging: 2 passes x 8KB. pass a: row = a*128 + (t>>2), 16B slot t&3.
  const int ar = t >> 2;  // 0..127  (swizzle bits identical for ar and ar+128)
  const int ascol = ((t & 3) ^ ((ar & 3) ^ ((ar >> 2) & 3))) * 8;  // elems
  const u16* pA0 = gW + (size_t)ar * L_ + ascol;
  char* dA = lds + w * 1024;  // + ring*16384 + pass*8192 (linear dest)

  // B staging: 2 passes x 8KB. pass p: rows p*16 + w*2 + (lane>>5),
  // granule (lane&31) ^ (oct-odd ? 4 : 0). oct = p*2 + (w>=4) (wave-uniform).
  const int bodd = (w >= 4) ? 4 : 0;
  const int bq = ((lane & 31) ^ bodd) * 4;        // f32 col of 16B granule
  const int brow = w * 2 + (lane >> 5);           // row within pass
  char* dB = lds + 32768 + w * 1024;              // + ring*16384 + p*8192

  // A fragment offsets (bf16 [r][k] 64B rows, slot-XOR swizzled)
  int offA[4];
#pragma unroll
  for (int mf = 0; mf < 4; ++mf) {
    int r = wm * 64 + mf * 16 + (lane & 15);
    offA[mf] = r * 64 + ((((lane >> 4) ^ (r & 3) ^ ((r >> 2) & 3))) << 4);
  }
  // B gather offsets (f32 [k][n] 512B rows): row oct*8+j, col n^((oct&1)<<4)
  int offB[4];
#pragma unroll
  for (int nf = 0; nf < 4; ++nf) {
    int n = wn * 64 + nf * 16 + (lane & 15);
    int oct = lane >> 4;
    offB[nf] = 32768 + oct * 4096 + ((n ^ ((oct & 1) << 4)) << 2);
  }

  f32x4 acc[4][4] = {};

#define A_ISSUE(tt)                                                         \
  do {                                                                      \
    GLOAD(pA0 + (tt) * 32, dA + ((tt) & 1) * 16384);                        \
    GLOAD(pA0 + (tt) * 32 + 128 * (size_t)L_, dA + ((tt) & 1) * 16384 + 8192); \
  } while (0)

#define B_ISSUE(tt)                                                         \
  do {                                                                      \
    GLOAD(gX + (size_t)((tt) * 32 + brow) * H_ + bq,                        \
          dB + ((tt) & 1) * 16384);                                         \
    GLOAD(gX + (size_t)((tt) * 32 + 16 + brow) * H_ + bq,                   \
          dB + ((tt) & 1) * 16384 + 8192);                                  \
  } while (0)

  // prologue
  A_ISSUE(0); B_ISSUE(0);
  asm volatile("s_waitcnt vmcnt(0)" ::: "memory");
  __builtin_amdgcn_s_barrier();

#pragma unroll
  for (int k = 0; k < NT; ++k) {
    if (k + 1 < NT) { A_ISSUE(k + 1); B_ISSUE(k + 1); }

    const char* baseA = lds + (k & 1) * 16384;
    const char* baseB = lds + (k & 1) * 16384;  // offB carries +32768

    s16x8 af[4];
#pragma unroll
    for (int mf = 0; mf < 4; ++mf) af[mf] = *(const s16x8*)(baseA + offA[mf]);

    s16x8 bf4[4];
#pragma unroll
    for (int nf = 0; nf < 4; ++nf) {
      union { u16 u[8]; s16x8 v; } pk;
#pragma unroll
      for (int j = 0; j < 8; ++j)
        pk.u[j] = f2bf(*(const float*)(baseB + offB[nf] + j * 512));
      bf4[nf] = pk.v;
    }
    asm volatile("s_waitcnt lgkmcnt(0)" ::: "memory");

    __builtin_amdgcn_s_setprio(1);
#pragma unroll
    for (int mf = 0; mf < 4; ++mf)
#pragma unroll
      for (int nf = 0; nf < 4; ++nf)
        acc[mf][nf] = __builtin_amdgcn_mfma_f32_16x16x32_bf16(af[mf], bf4[nf], acc[mf][nf], 0, 0, 0);
    __builtin_amdgcn_s_setprio(0);

    if (k + 1 < NT) {
      asm volatile("s_waitcnt vmcnt(0)" ::: "memory");  // tile k+1 resident
      __builtin_amdgcn_s_barrier();
    }
  }
#undef A_ISSUE
#undef B_ISSUE

  // epilogue: C/D layout col=lane&15, row=(lane>>4)*4+reg  [verified m89/m91]
  const int orow0 = mt * 256 + wm * 64 + ((lane >> 4) << 2);
  const int ocol0 = nt * 128 + wn * 64 + (lane & 15);
#pragma unroll
  for (int mf = 0; mf < 4; ++mf)
#pragma unroll
    for (int nf = 0; nf < 4; ++nf)
#pragma unroll
      for (int j = 0; j < 4; ++j) {
        int row = orow0 + mf * 16 + j;
        int col = ocol0 + nf * 16;
        out[((size_t)b * L_ + row) * H_ + col] = acc[mf][nf][j];
      }
}

extern "C" void kernel_launch(void* const* d_in, const int* in_sizes, int n_in,
                              void* d_out, int out_size, void* d_ws, size_t ws_size,
                              hipStream_t stream) {
  (void)in_sizes; (void)n_in; (void)out_size; (void)ws_size;
  const float* sent = (const float*)d_in[0];  // [B, L, H] f32
  const float* mask = (const float*)d_in[1];  // [B, L]    f32
  const float* att  = (const float*)d_in[2];  // [B, L, L] f32
  u16* Wm = (u16*)d_ws;                       // [B, L, L] bf16 (32 MiB)
  float* outp = (float*)d_out;                // [B, L, H] f32

  softmax_rows<<<2048, 256, 0, stream>>>(att, mask, Wm);
  gemm_xd<<<B_ * 2 * 8, 512, 0, stream>>>(Wm, sent, outp);
}